// Round 2
// baseline (616.444 us; speedup 1.0000x reference)
//
#include <hip/hip_runtime.h>
#include <hip/hip_bf16.h>
#include <stdint.h>

// RoPE attention, B=2 S=2048 D=2048 H=16 hd=128.
// conv(f32->bf16) -> Q GEMM | K GEMM(+rope epilogue) | V GEMM(->Vt layout)
//   -> flash attention (rope(Q) fused, swapped-QK^T in-register softmax,
//      T14 double-buffered staging, T13 defer-max) -> output GEMM (f32).

typedef __attribute__((ext_vector_type(4))) float f32x4;
typedef __attribute__((ext_vector_type(8))) short bf16x8;

typedef __attribute__((address_space(3))) unsigned int lds_u32;
typedef __attribute__((address_space(1))) const unsigned int gbl_u32;

__device__ __forceinline__ void async16(const void* g, void* l) {
  __builtin_amdgcn_global_load_lds((gbl_u32*)g, (lds_u32*)l, 16, 0, 0);
}

__device__ __forceinline__ float bf_to_f(unsigned short u) {
  union { unsigned int i; float f; } v; v.i = ((unsigned int)u) << 16; return v.f;
}
__device__ __forceinline__ unsigned short f_to_bf(float f) {
  union { float f; unsigned int i; } v; v.f = f;
  unsigned int r = v.i + 0x7FFFu + ((v.i >> 16) & 1u);  // RNE
  return (unsigned short)(r >> 16);
}

#define B_ 2
#define S_ 2048
#define D_ 2048
#define H_ 16
#define HD_ 128

// ---------------- f32 -> bf16 convert (4 elems/thread) ----------------
__global__ __launch_bounds__(256) void conv_kernel(const float* __restrict__ src,
                                                   unsigned short* __restrict__ dst, int n4) {
  int i = blockIdx.x * 256 + threadIdx.x;
  if (i >= n4) return;
  float4 v = ((const float4*)src)[i];
  uint2 o;
  o.x = (unsigned int)f_to_bf(v.x) | ((unsigned int)f_to_bf(v.y) << 16);
  o.y = (unsigned int)f_to_bf(v.z) | ((unsigned int)f_to_bf(v.w) << 16);
  ((uint2*)dst)[i] = o;
}

// ---------------- rope cos/sin table: [S][64] ----------------
__global__ __launch_bounds__(256) void rope_table_kernel(float* __restrict__ cosT,
                                                         float* __restrict__ sinT) {
  int i = blockIdx.x * 256 + threadIdx.x;  // S*64 entries
  int s = i >> 6, j = i & 63;
  float inv = powf(10000.0f, -(float)(2 * j) * (1.0f / 128.0f));
  float ang = (float)s * inv;
  float sv, cv;
  sincosf(ang, &sv, &cv);
  cosT[i] = cv;
  sinT[i] = sv;
}

// ---------------- GEMM: C[M,N] = A[M,K] * Bmat[N,K]^T -----------------------
// MODE 0: bf16 out. MODE 1: f32 out. MODE 2: bf16 out + RoPE (K projection).
// MODE 3: bf16 out written transposed into Vt[b*2048 + n][s] (V projection).
template <int MODE>
__global__ __launch_bounds__(256, 2) void gemm_bt(const unsigned short* __restrict__ A,
                                                  const unsigned short* __restrict__ Bm,
                                                  unsigned short* __restrict__ Cb,
                                                  float* __restrict__ Cf,
                                                  const float* __restrict__ cosT,
                                                  const float* __restrict__ sinT,
                                                  int M, int N, int K) {
  __shared__ unsigned short sA[128 * 32];
  __shared__ unsigned short sB[128 * 32];
  const int tid = threadIdx.x;
  const int l = tid & 63, wv = tid >> 6;
  const int lane15 = l & 15, lhi = l >> 4;
  const int wm = wv >> 1, wn = wv & 1;
  const int bm = blockIdx.x, bn = blockIdx.y;
  const unsigned short* Ag = A + (size_t)bm * 128 * K;
  const unsigned short* Bg = Bm + (size_t)bn * 128 * K;

  f32x4 acc[4][4];
  const f32x4 zero = {0.f, 0.f, 0.f, 0.f};
#pragma unroll
  for (int i = 0; i < 4; i++)
#pragma unroll
    for (int j = 0; j < 4; j++) acc[i][j] = zero;

  for (int k0 = 0; k0 < K; k0 += 32) {
    __syncthreads();
#pragma unroll
    for (int i = 0; i < 2; i++) {
      int c = i * 256 + tid;
      int row = c >> 2, col = (c & 3) << 3;
      async16(Ag + (size_t)row * K + k0 + col, &sA[c * 8]);
      async16(Bg + (size_t)row * K + k0 + col, &sB[c * 8]);
    }
    __syncthreads();

    bf16x8 af[4], bfr[4];
#pragma unroll
    for (int i = 0; i < 4; i++)
      af[i] = *(const bf16x8*)&sA[(wm * 64 + i * 16 + lane15) * 32 + lhi * 8];
#pragma unroll
    for (int j = 0; j < 4; j++)
      bfr[j] = *(const bf16x8*)&sB[(wn * 64 + j * 16 + lane15) * 32 + lhi * 8];
#pragma unroll
    for (int i = 0; i < 4; i++)
#pragma unroll
      for (int j = 0; j < 4; j++)
        acc[i][j] = __builtin_amdgcn_mfma_f32_16x16x32_bf16(af[i], bfr[j], acc[i][j], 0, 0, 0);
  }

  // epilogue: C/D layout col=lane&15, row=(lane>>4)*4+r
#pragma unroll
  for (int i = 0; i < 4; i++) {
    int m0 = bm * 128 + wm * 64 + i * 16 + lhi * 4;
#pragma unroll
    for (int j = 0; j < 4; j++) {
      int n = bn * 128 + wn * 64 + j * 16 + lane15;
      if constexpr (MODE == 0) {
#pragma unroll
        for (int r = 0; r < 4; r++) Cb[(size_t)(m0 + r) * N + n] = f_to_bf(acc[i][j][r]);
      } else if constexpr (MODE == 1) {
#pragma unroll
        for (int r = 0; r < 4; r++) Cf[(size_t)(m0 + r) * N + n] = acc[i][j][r];
      } else if constexpr (MODE == 2) {
        int s0 = m0 & (S_ - 1);
        int jp = (n & (HD_ - 1)) >> 1;
        int odd = n & 1;
#pragma unroll
        for (int r = 0; r < 4; r++) {
          float own = acc[i][j][r];
          float prt = __shfl_xor(own, 1);
          float c = cosT[(s0 + r) * 64 + jp];
          float sn = sinT[(s0 + r) * 64 + jp];
          float outv = odd ? fmaf(prt, sn, own * c) : own * c - prt * sn;
          Cb[(size_t)(m0 + r) * N + n] = f_to_bf(outv);
        }
      } else {  // MODE 3: Vt[b*2048 + n][s], 4 consecutive s packed
        int s0 = m0 & (S_ - 1);
        size_t row = (size_t)((m0 >> 11) * D_ + n);
        uint2 st;
        st.x = (unsigned int)f_to_bf(acc[i][j][0]) | ((unsigned int)f_to_bf(acc[i][j][1]) << 16);
        st.y = (unsigned int)f_to_bf(acc[i][j][2]) | ((unsigned int)f_to_bf(acc[i][j][3]) << 16);
        *(uint2*)(Cb + row * S_ + s0) = st;
      }
    }
  }
}

// ---------------- flash attention ----------------
__device__ __forceinline__ void load_tile(const unsigned short* Kg, const unsigned short* Vg,
                                          int tid, int t, uint4 (&kr)[4], uint4 (&vr)[4]) {
#pragma unroll
  for (int i = 0; i < 4; i++) {
    int c = i * 256 + tid;
    kr[i] = *(const uint4*)(Kg + (size_t)(t * 64 + (c >> 4)) * D_ + ((c & 15) << 3));
    vr[i] = *(const uint4*)(Vg + (size_t)(c >> 3) * S_ + t * 64 + ((c & 7) << 3));
  }
}
__device__ __forceinline__ void write_tile(unsigned short* sK, unsigned short* sV, int tid,
                                           const uint4 (&kr)[4], const uint4 (&vr)[4]) {
#pragma unroll
  for (int i = 0; i < 4; i++) {
    int c = i * 256 + tid;
    int rk = c >> 4, ck = (c & 15) << 4;
    *(uint4*)((char*)sK + rk * 256 + (ck ^ ((rk & 7) << 4))) = kr[i];
    int rv = c >> 3, cv = (c & 7) << 4;
    *(uint4*)((char*)sV + rv * 128 + (cv ^ ((rv & 7) << 4))) = vr[i];
  }
}

// grid: x = q-tile (S/64), y = bh (32). 4 waves, each owns 16 q-rows.
__global__ __launch_bounds__(256, 2) void attn_kernel(const unsigned short* __restrict__ Q,
                                                      const unsigned short* __restrict__ K,
                                                      const unsigned short* __restrict__ Vt,
                                                      unsigned short* __restrict__ ctx,
                                                      const float* __restrict__ cosT,
                                                      const float* __restrict__ sinT) {
  __shared__ unsigned short sK[64 * 128];
  __shared__ unsigned short sV[128 * 64];
  __shared__ unsigned short sP[4][16 * 72];
  const int tid = threadIdx.x, l = tid & 63, w = tid >> 6;
  const int lane15 = l & 15, lhi = l >> 4;
  const int bh = blockIdx.y, b = bh >> 4, h = bh & 15;
  const int q0 = blockIdx.x * 64;
  const int s_q = q0 + w * 16 + lane15;
  const unsigned short* Qrow = Q + ((size_t)(b * S_ + s_q)) * D_ + h * HD_;
  const unsigned short* Kg = K + ((size_t)(b * S_)) * D_ + h * HD_;
  const unsigned short* Vg = Vt + ((size_t)bh * HD_) * S_;
  const float scale = 0.08838834764831845f;  // 1/sqrt(128)

  // Q load + RoPE + scale (once per block; pairs are in-lane)
  bf16x8 qf[4];
#pragma unroll
  for (int kc = 0; kc < 4; kc++) {
    int d0 = kc * 32 + lhi * 8;
    uint4 raw = *(const uint4*)(Qrow + d0);
    float4 cv = *(const float4*)(cosT + (size_t)s_q * 64 + (d0 >> 1));
    float4 sv = *(const float4*)(sinT + (size_t)s_q * 64 + (d0 >> 1));
    unsigned int u[4] = {raw.x, raw.y, raw.z, raw.w};
    float cc[4] = {cv.x, cv.y, cv.z, cv.w};
    float ss[4] = {sv.x, sv.y, sv.z, sv.w};
    unsigned int o[4];
#pragma unroll
    for (int p = 0; p < 4; p++) {
      float re = bf_to_f((unsigned short)(u[p] & 0xffffu));
      float im = bf_to_f((unsigned short)(u[p] >> 16));
      float orr = (re * cc[p] - im * ss[p]) * scale;
      float oi = (re * ss[p] + im * cc[p]) * scale;
      o[p] = (unsigned int)f_to_bf(orr) | ((unsigned int)f_to_bf(oi) << 16);
    }
    union { uint4 u4; bf16x8 v; } cvt;
    cvt.u4.x = o[0]; cvt.u4.y = o[1]; cvt.u4.z = o[2]; cvt.u4.w = o[3];
    qf[kc] = cvt.v;
  }

  float mrun = -1e30f, lrun = 0.f;
  const f32x4 zero = {0.f, 0.f, 0.f, 0.f};
  f32x4 oacc[8];
#pragma unroll
  for (int nf = 0; nf < 8; nf++) oacc[nf] = zero;

  auto compute_tile = [&]() {
    // S^T = K Q^T : lane owns q = lane15, k = n*16 + lhi*4 + r
    f32x4 sacc[4];
#pragma unroll
    for (int n = 0; n < 4; n++) sacc[n] = zero;
#pragma unroll
    for (int n = 0; n < 4; n++) {
      int row = n * 16 + lane15;
#pragma unroll
      for (int kc = 0; kc < 4; kc++) {
        bf16x8 kf = *(const bf16x8*)((char*)sK + row * 256 +
                                     ((kc * 64 + lhi * 16) ^ ((row & 7) << 4)));
        sacc[n] = __builtin_amdgcn_mfma_f32_16x16x32_bf16(kf, qf[kc], sacc[n], 0, 0, 0);
      }
    }
    // in-register online softmax (defer-max, THR=8)
    float pmax = sacc[0][0];
#pragma unroll
    for (int n = 0; n < 4; n++)
#pragma unroll
      for (int r = 0; r < 4; r++) pmax = fmaxf(pmax, sacc[n][r]);
    pmax = fmaxf(pmax, __shfl_xor(pmax, 16));
    pmax = fmaxf(pmax, __shfl_xor(pmax, 32));
    if (!__all(pmax - mrun <= 8.0f)) {
      float mnew = fmaxf(mrun, pmax);
      float alpha = __expf(mrun - mnew);
      lrun *= alpha;
      float af[4];
#pragma unroll
      for (int r = 0; r < 4; r++) af[r] = __shfl(alpha, lhi * 4 + r);  // oacc rows: q=lhi*4+r
#pragma unroll
      for (int nf = 0; nf < 8; nf++)
#pragma unroll
        for (int r = 0; r < 4; r++) oacc[nf][r] *= af[r];
      mrun = mnew;
    }
    const float l2e = 1.44269504f;
    float mb = mrun * l2e;
    float rs = 0.f;
    float p[4][4];
#pragma unroll
    for (int n = 0; n < 4; n++)
#pragma unroll
      for (int r = 0; r < 4; r++) {
        float pv = exp2f(sacc[n][r] * l2e - mb);
        p[n][r] = pv;
        rs += pv;
      }
    rs += __shfl_xor(rs, 16);
    rs += __shfl_xor(rs, 32);
    lrun += rs;
    // P -> per-wave LDS in A-operand layout (row=q, k contiguous), stride 72
#pragma unroll
    for (int n = 0; n < 4; n++) {
      uint2 st;
      st.x = (unsigned int)f_to_bf(p[n][0]) | ((unsigned int)f_to_bf(p[n][1]) << 16);
      st.y = (unsigned int)f_to_bf(p[n][2]) | ((unsigned int)f_to_bf(p[n][3]) << 16);
      *(uint2*)&sP[w][lane15 * 72 + n * 16 + lhi * 4] = st;
    }
    asm volatile("s_waitcnt lgkmcnt(0)" ::: "memory");
    __builtin_amdgcn_sched_barrier(0);
    bf16x8 pf[2];
#pragma unroll
    for (int kc = 0; kc < 2; kc++)
      pf[kc] = *(const bf16x8*)&sP[w][lane15 * 72 + kc * 32 + lhi * 8];
    // O += P * V (B from Vt rows)
#pragma unroll
    for (int nf = 0; nf < 8; nf++) {
      int row = nf * 16 + lane15;
#pragma unroll
      for (int kc = 0; kc < 2; kc++) {
        bf16x8 vf = *(const bf16x8*)((char*)sV + row * 128 +
                                     ((kc * 64 + lhi * 16) ^ ((row & 7) << 4)));
        oacc[nf] = __builtin_amdgcn_mfma_f32_16x16x32_bf16(pf[kc], vf, oacc[nf], 0, 0, 0);
      }
    }
  };

  // T14: double-buffered reg staging, 2x-unrolled k-loop (NT=32)
  uint4 ka[4], va[4], kb[4], vb[4];
  load_tile(Kg, Vg, tid, 0, ka, va);
  for (int t = 0; t < 32; t += 2) {
    load_tile(Kg, Vg, tid, t + 1, kb, vb);
    __syncthreads();
    write_tile(sK, sV, tid, ka, va);
    __syncthreads();
    compute_tile();
    if (t + 2 < 32) load_tile(Kg, Vg, tid, t + 2, ka, va);
    __syncthreads();
    write_tile(sK, sV, tid, kb, vb);
    __syncthreads();
    compute_tile();
  }

  // epilogue: oacc rows q=lhi*4+r, cols d=nf*16+lane15; lrun lives at lane q
  float inv = 1.0f / lrun;
  float invr[4];
#pragma unroll
  for (int r = 0; r < 4; r++) invr[r] = __shfl(inv, lhi * 4 + r);
  unsigned short* Og = ctx + ((size_t)(b * S_ + q0 + w * 16)) * D_ + h * HD_;
#pragma unroll
  for (int r = 0; r < 4; r++) {
    int qrow = lhi * 4 + r;
#pragma unroll
    for (int nf = 0; nf < 8; nf++)
      Og[(size_t)qrow * D_ + nf * 16 + lane15] = f_to_bf(oacc[nf][r] * invr[r]);
  }
}

// ---------------- launcher ----------------
extern "C" void kernel_launch(void* const* d_in, const int* in_sizes, int n_in,
                              void* d_out, int out_size, void* d_ws, size_t ws_size,
                              hipStream_t stream) {
  (void)in_sizes; (void)n_in; (void)out_size; (void)ws_size;
  const float* x = (const float*)d_in[0];
  const float* wq = (const float*)d_in[1];
  const float* wk = (const float*)d_in[2];
  const float* wv = (const float*)d_in[3];
  const float* wo = (const float*)d_in[4];
  float* out = (float*)d_out;

  char* ws = (char*)d_ws;
  const size_t MB = 1024 * 1024;
  unsigned short* xb  = (unsigned short*)(ws + 0 * MB);    // 16 MB; later aliased as ctx
  unsigned short* wqb = (unsigned short*)(ws + 16 * MB);   // 8 MB
  unsigned short* wkb = (unsigned short*)(ws + 24 * MB);   // 8 MB
  unsigned short* wvb = (unsigned short*)(ws + 32 * MB);   // 8 MB
  unsigned short* wob = (unsigned short*)(ws + 40 * MB);   // 8 MB
  unsigned short* Qb  = (unsigned short*)(ws + 48 * MB);   // 16 MB
  unsigned short* Kb  = (unsigned short*)(ws + 64 * MB);   // 16 MB
  unsigned short* Vtb = (unsigned short*)(ws + 80 * MB);   // 16 MB
  float* cosT = (float*)(ws + 96 * MB);                    // 0.5 MB
  float* sinT = (float*)(ws + 96 * MB + 524288);           // 0.5 MB
  unsigned short* ctxb = xb;  // x_bf16 dead after QKV GEMMs

  const int M = B_ * S_;  // 4096

  conv_kernel<<<8192, 256, 0, stream>>>(x, xb, (B_ * S_ * D_) / 4);
  conv_kernel<<<4096, 256, 0, stream>>>(wq, wqb, (D_ * D_) / 4);
  conv_kernel<<<4096, 256, 0, stream>>>(wk, wkb, (D_ * D_) / 4);
  conv_kernel<<<4096, 256, 0, stream>>>(wv, wvb, (D_ * D_) / 4);
  conv_kernel<<<4096, 256, 0, stream>>>(wo, wob, (D_ * D_) / 4);
  rope_table_kernel<<<512, 256, 0, stream>>>(cosT, sinT);

  dim3 ggrid(M / 128, D_ / 128);
  gemm_bt<0><<<ggrid, 256, 0, stream>>>(xb, wqb, Qb, nullptr, nullptr, nullptr, M, D_, D_);
  gemm_bt<2><<<ggrid, 256, 0, stream>>>(xb, wkb, Kb, nullptr, cosT, sinT, M, D_, D_);
  gemm_bt<3><<<ggrid, 256, 0, stream>>>(xb, wvb, Vtb, nullptr, nullptr, nullptr, M, D_, D_);

  attn_kernel<<<dim3(S_ / 64, B_ * H_), 256, 0, stream>>>(Qb, Kb, Vtb, ctxb, cosT, sinT);

  gemm_bt<1><<<ggrid, 256, 0, stream>>>(ctxb, wob, nullptr, out, nullptr, nullptr, M, D_, D_);
}

// Round 3
// 362.779 us; speedup vs baseline: 1.6992x; 1.6992x over previous
//
#include <hip/hip_runtime.h>
#include <hip/hip_bf16.h>
#include <stdint.h>

// RoPE attention, B=2 S=2048 D=2048 H=16 hd=128.
// conv(f32->bf16) -> Q GEMM | K GEMM(+rope epilogue) | V GEMM(->Vt layout)
//   -> flash attention (rope(Q) fused, swapped-QK^T in-register softmax,
//      global_load_lds staging w/ pre-swizzled source, defer-max)
//   -> output GEMM (f32).

typedef __attribute__((ext_vector_type(4))) float f32x4;
typedef __attribute__((ext_vector_type(8))) short bf16x8;

typedef __attribute__((address_space(3))) unsigned int lds_u32;
typedef __attribute__((address_space(1))) const unsigned int gbl_u32;

__device__ __forceinline__ void async16(const void* g, void* l) {
  __builtin_amdgcn_global_load_lds((gbl_u32*)g, (lds_u32*)l, 16, 0, 0);
}

__device__ __forceinline__ float bf_to_f(unsigned short u) {
  union { unsigned int i; float f; } v; v.i = ((unsigned int)u) << 16; return v.f;
}
__device__ __forceinline__ unsigned short f_to_bf(float f) {
  union { float f; unsigned int i; } v; v.f = f;
  unsigned int r = v.i + 0x7FFFu + ((v.i >> 16) & 1u);  // RNE
  return (unsigned short)(r >> 16);
}

#define B_ 2
#define S_ 2048
#define D_ 2048
#define H_ 16
#define HD_ 128

// ---------------- f32 -> bf16 convert (4 elems/thread) ----------------
__global__ __launch_bounds__(256) void conv_kernel(const float* __restrict__ src,
                                                   unsigned short* __restrict__ dst, int n4) {
  int i = blockIdx.x * 256 + threadIdx.x;
  if (i >= n4) return;
  float4 v = ((const float4*)src)[i];
  uint2 o;
  o.x = (unsigned int)f_to_bf(v.x) | ((unsigned int)f_to_bf(v.y) << 16);
  o.y = (unsigned int)f_to_bf(v.z) | ((unsigned int)f_to_bf(v.w) << 16);
  ((uint2*)dst)[i] = o;
}

// ---------------- rope cos/sin table: [S][64] ----------------
__global__ __launch_bounds__(256) void rope_table_kernel(float* __restrict__ cosT,
                                                         float* __restrict__ sinT) {
  int i = blockIdx.x * 256 + threadIdx.x;  // S*64 entries
  int s = i >> 6, j = i & 63;
  float inv = powf(10000.0f, -(float)(2 * j) * (1.0f / 128.0f));
  float ang = (float)s * inv;
  float sv, cv;
  sincosf(ang, &sv, &cv);
  cosT[i] = cv;
  sinT[i] = sv;
}

// ---------------- GEMM: C[M,N] = A[M,K] * Bmat[N,K]^T -----------------------
// MODE 0: bf16 out. MODE 1: f32 out. MODE 2: bf16 out + RoPE (K projection).
// MODE 3: bf16 out written transposed into Vt[b*2048 + n][s] (V projection).
template <int MODE>
__global__ __launch_bounds__(256, 2) void gemm_bt(const unsigned short* __restrict__ A,
                                                  const unsigned short* __restrict__ Bm,
                                                  unsigned short* __restrict__ Cb,
                                                  float* __restrict__ Cf,
                                                  const float* __restrict__ cosT,
                                                  const float* __restrict__ sinT,
                                                  int M, int N, int K) {
  __shared__ unsigned short sA[128 * 32];
  __shared__ unsigned short sB[128 * 32];
  const int tid = threadIdx.x;
  const int l = tid & 63, wv = tid >> 6;
  const int lane15 = l & 15, lhi = l >> 4;
  const int wm = wv >> 1, wn = wv & 1;
  const int bm = blockIdx.x, bn = blockIdx.y;
  const unsigned short* Ag = A + (size_t)bm * 128 * K;
  const unsigned short* Bg = Bm + (size_t)bn * 128 * K;

  f32x4 acc[4][4];
  const f32x4 zero = {0.f, 0.f, 0.f, 0.f};
#pragma unroll
  for (int i = 0; i < 4; i++)
#pragma unroll
    for (int j = 0; j < 4; j++) acc[i][j] = zero;

  for (int k0 = 0; k0 < K; k0 += 32) {
    __syncthreads();
#pragma unroll
    for (int i = 0; i < 2; i++) {
      int c = i * 256 + tid;
      int row = c >> 2, col = (c & 3) << 3;
      async16(Ag + (size_t)row * K + k0 + col, &sA[c * 8]);
      async16(Bg + (size_t)row * K + k0 + col, &sB[c * 8]);
    }
    __syncthreads();

    bf16x8 af[4], bfr[4];
#pragma unroll
    for (int i = 0; i < 4; i++)
      af[i] = *(const bf16x8*)&sA[(wm * 64 + i * 16 + lane15) * 32 + lhi * 8];
#pragma unroll
    for (int j = 0; j < 4; j++)
      bfr[j] = *(const bf16x8*)&sB[(wn * 64 + j * 16 + lane15) * 32 + lhi * 8];
#pragma unroll
    for (int i = 0; i < 4; i++)
#pragma unroll
      for (int j = 0; j < 4; j++)
        acc[i][j] = __builtin_amdgcn_mfma_f32_16x16x32_bf16(af[i], bfr[j], acc[i][j], 0, 0, 0);
  }

  // epilogue: C/D layout col=lane&15, row=(lane>>4)*4+r
#pragma unroll
  for (int i = 0; i < 4; i++) {
    int m0 = bm * 128 + wm * 64 + i * 16 + lhi * 4;
#pragma unroll
    for (int j = 0; j < 4; j++) {
      int n = bn * 128 + wn * 64 + j * 16 + lane15;
      if constexpr (MODE == 0) {
#pragma unroll
        for (int r = 0; r < 4; r++) Cb[(size_t)(m0 + r) * N + n] = f_to_bf(acc[i][j][r]);
      } else if constexpr (MODE == 1) {
#pragma unroll
        for (int r = 0; r < 4; r++) Cf[(size_t)(m0 + r) * N + n] = acc[i][j][r];
      } else if constexpr (MODE == 2) {
        int s0 = m0 & (S_ - 1);
        int jp = (n & (HD_ - 1)) >> 1;
        int odd = n & 1;
#pragma unroll
        for (int r = 0; r < 4; r++) {
          float own = acc[i][j][r];
          float prt = __shfl_xor(own, 1);
          float c = cosT[(s0 + r) * 64 + jp];
          float sn = sinT[(s0 + r) * 64 + jp];
          float outv = odd ? fmaf(prt, sn, own * c) : own * c - prt * sn;
          Cb[(size_t)(m0 + r) * N + n] = f_to_bf(outv);
        }
      } else {  // MODE 3: Vt[b*2048 + n][s], 4 consecutive s packed
        int s0 = m0 & (S_ - 1);
        size_t row = (size_t)((m0 >> 11) * D_ + n);
        uint2 st;
        st.x = (unsigned int)f_to_bf(acc[i][j][0]) | ((unsigned int)f_to_bf(acc[i][j][1]) << 16);
        st.y = (unsigned int)f_to_bf(acc[i][j][2]) | ((unsigned int)f_to_bf(acc[i][j][3]) << 16);
        *(uint2*)(Cb + row * S_ + s0) = st;
      }
    }
  }
}

// ---------------- flash attention ----------------
// grid: x = q-tile (S/64), y = bh (32). 4 waves, each owns 16 q-rows.
// K tile [64][128] and Vt tile [128][64] staged via global_load_lds with
// pre-swizzled SOURCE column (linear LDS dest); reads apply the same XOR.
__global__ __launch_bounds__(256, 3) void attn_kernel(const unsigned short* __restrict__ Q,
                                                      const unsigned short* __restrict__ K,
                                                      const unsigned short* __restrict__ Vt,
                                                      unsigned short* __restrict__ ctx,
                                                      const float* __restrict__ cosT,
                                                      const float* __restrict__ sinT) {
  __shared__ unsigned short sK[64 * 128];
  __shared__ unsigned short sV[128 * 64];
  __shared__ unsigned short sP[4][16 * 72];
  const int tid = threadIdx.x, l = tid & 63, w = tid >> 6;
  const int lane15 = l & 15, lhi = l >> 4;
  const int bh = blockIdx.y, b = bh >> 4, h = bh & 15;
  const int q0 = blockIdx.x * 64;
  const int s_q = q0 + w * 16 + lane15;
  const unsigned short* Qrow = Q + ((size_t)(b * S_ + s_q)) * D_ + h * HD_;
  const unsigned short* Kg = K + ((size_t)(b * S_)) * D_ + h * HD_;
  const unsigned short* Vg = Vt + ((size_t)bh * HD_) * S_;
  const float scale = 0.08838834764831845f;  // 1/sqrt(128)

  // Q load + RoPE + scale (once per block; pairs are in-lane)
  bf16x8 qf[4];
#pragma unroll
  for (int kc = 0; kc < 4; kc++) {
    int d0 = kc * 32 + lhi * 8;
    uint4 raw = *(const uint4*)(Qrow + d0);
    float4 cv = *(const float4*)(cosT + (size_t)s_q * 64 + (d0 >> 1));
    float4 sv = *(const float4*)(sinT + (size_t)s_q * 64 + (d0 >> 1));
    unsigned int u[4] = {raw.x, raw.y, raw.z, raw.w};
    float cc[4] = {cv.x, cv.y, cv.z, cv.w};
    float ss[4] = {sv.x, sv.y, sv.z, sv.w};
    unsigned int o[4];
#pragma unroll
    for (int p = 0; p < 4; p++) {
      float re = bf_to_f((unsigned short)(u[p] & 0xffffu));
      float im = bf_to_f((unsigned short)(u[p] >> 16));
      float orr = (re * cc[p] - im * ss[p]) * scale;
      float oi = (re * ss[p] + im * cc[p]) * scale;
      o[p] = (unsigned int)f_to_bf(orr) | ((unsigned int)f_to_bf(oi) << 16);
    }
    union { uint4 u4; bf16x8 v; } cvt;
    cvt.u4.x = o[0]; cvt.u4.y = o[1]; cvt.u4.z = o[2]; cvt.u4.w = o[3];
    qf[kc] = cvt.v;
  }

  float mrun = -1e30f, lrun = 0.f;
  const f32x4 zero = {0.f, 0.f, 0.f, 0.f};
  f32x4 oacc[8];
#pragma unroll
  for (int nf = 0; nf < 8; nf++) oacc[nf] = zero;

  for (int t = 0; t < 32; ++t) {
    __syncthreads();  // previous tile fully consumed
    // stage K tile: wave w covers rows [w*16, w*16+16), 4 insts x (64 lanes x 16B)
#pragma unroll
    for (int i = 0; i < 4; i++) {
      int row = w * 16 + i * 4 + (l >> 4);
      int colD = (l & 15) << 4;                      // dest byte col (linear)
      int colS = colD ^ ((row & 7) << 4);            // pre-swizzled source col
      async16(Kg + (size_t)(t * 64 + row) * D_ + (colS >> 1),
              (char*)sK + row * 256 + colD);
    }
    // stage Vt tile: wave w covers rows [w*32, w*32+32), 4 insts x (64 lanes x 16B)
#pragma unroll
    for (int i = 0; i < 4; i++) {
      int row = w * 32 + i * 8 + (l >> 3);
      int colD = (l & 7) << 4;
      int colS = colD ^ ((row & 7) << 4);
      async16(Vg + (size_t)row * S_ + t * 64 + (colS >> 1),
              (char*)sV + row * 128 + colD);
    }
    __syncthreads();  // staging complete (barrier drains vmcnt)

    // S^T = K Q^T : lane owns q = lane15, k = n*16 + lhi*4 + r
    f32x4 sacc[4];
#pragma unroll
    for (int n = 0; n < 4; n++) sacc[n] = zero;
#pragma unroll
    for (int n = 0; n < 4; n++) {
      int row = n * 16 + lane15;
#pragma unroll
      for (int kc = 0; kc < 4; kc++) {
        bf16x8 kf = *(const bf16x8*)((char*)sK + row * 256 +
                                     ((kc * 64 + lhi * 16) ^ ((row & 7) << 4)));
        sacc[n] = __builtin_amdgcn_mfma_f32_16x16x32_bf16(kf, qf[kc], sacc[n], 0, 0, 0);
      }
    }

    // in-register online softmax (defer-max, THR=8)
    float pmax = sacc[0][0];
#pragma unroll
    for (int n = 0; n < 4; n++)
#pragma unroll
      for (int r = 0; r < 4; r++) pmax = fmaxf(pmax, sacc[n][r]);
    pmax = fmaxf(pmax, __shfl_xor(pmax, 16));
    pmax = fmaxf(pmax, __shfl_xor(pmax, 32));
    if (!__all(pmax - mrun <= 8.0f)) {
      float mnew = fmaxf(mrun, pmax);
      float alpha = __expf(mrun - mnew);
      lrun *= alpha;
      float af[4];
#pragma unroll
      for (int r = 0; r < 4; r++) af[r] = __shfl(alpha, lhi * 4 + r);  // oacc rows q=lhi*4+r
#pragma unroll
      for (int nf = 0; nf < 8; nf++)
#pragma unroll
        for (int r = 0; r < 4; r++) oacc[nf][r] *= af[r];
      mrun = mnew;
    }
    const float l2e = 1.44269504f;
    float mb = mrun * l2e;
    float rs = 0.f;
    float p[4][4];
#pragma unroll
    for (int n = 0; n < 4; n++)
#pragma unroll
      for (int r = 0; r < 4; r++) {
        float pv = exp2f(sacc[n][r] * l2e - mb);
        p[n][r] = pv;
        rs += pv;
      }
    rs += __shfl_xor(rs, 16);
    rs += __shfl_xor(rs, 32);
    lrun += rs;

    // P -> per-wave LDS in A-operand layout (row=q, k contiguous), stride 72
#pragma unroll
    for (int n = 0; n < 4; n++) {
      uint2 st;
      st.x = (unsigned int)f_to_bf(p[n][0]) | ((unsigned int)f_to_bf(p[n][1]) << 16);
      st.y = (unsigned int)f_to_bf(p[n][2]) | ((unsigned int)f_to_bf(p[n][3]) << 16);
      *(uint2*)&sP[w][lane15 * 72 + n * 16 + lhi * 4] = st;
    }
    asm volatile("s_waitcnt lgkmcnt(0)" ::: "memory");
    __builtin_amdgcn_sched_barrier(0);
    bf16x8 pf[2];
#pragma unroll
    for (int kc = 0; kc < 2; kc++)
      pf[kc] = *(const bf16x8*)&sP[w][lane15 * 72 + kc * 32 + lhi * 8];

    // O += P * V (B from Vt rows)
#pragma unroll
    for (int nf = 0; nf < 8; nf++) {
      int row = nf * 16 + lane15;
#pragma unroll
      for (int kc = 0; kc < 2; kc++) {
        bf16x8 vf = *(const bf16x8*)((char*)sV + row * 128 +
                                     ((kc * 64 + lhi * 16) ^ ((row & 7) << 4)));
        oacc[nf] = __builtin_amdgcn_mfma_f32_16x16x32_bf16(pf[kc], vf, oacc[nf], 0, 0, 0);
      }
    }
  }

  // epilogue: oacc rows q=lhi*4+r, cols d=nf*16+lane15; lrun lives at lane q
  float inv = 1.0f / lrun;
  float invr[4];
#pragma unroll
  for (int r = 0; r < 4; r++) invr[r] = __shfl(inv, lhi * 4 + r);
  unsigned short* Og = ctx + ((size_t)(b * S_ + q0 + w * 16)) * D_ + h * HD_;
#pragma unroll
  for (int r = 0; r < 4; r++) {
    int qrow = lhi * 4 + r;
#pragma unroll
    for (int nf = 0; nf < 8; nf++)
      Og[(size_t)qrow * D_ + nf * 16 + lane15] = f_to_bf(oacc[nf][r] * invr[r]);
  }
}

// ---------------- launcher ----------------
extern "C" void kernel_launch(void* const* d_in, const int* in_sizes, int n_in,
                              void* d_out, int out_size, void* d_ws, size_t ws_size,
                              hipStream_t stream) {
  (void)in_sizes; (void)n_in; (void)out_size; (void)ws_size;
  const float* x = (const float*)d_in[0];
  const float* wq = (const float*)d_in[1];
  const float* wk = (const float*)d_in[2];
  const float* wv = (const float*)d_in[3];
  const float* wo = (const float*)d_in[4];
  float* out = (float*)d_out;

  char* ws = (char*)d_ws;
  const size_t MB = 1024 * 1024;
  unsigned short* xb  = (unsigned short*)(ws + 0 * MB);    // 16 MB; later aliased as ctx
  unsigned short* wqb = (unsigned short*)(ws + 16 * MB);   // 8 MB
  unsigned short* wkb = (unsigned short*)(ws + 24 * MB);   // 8 MB
  unsigned short* wvb = (unsigned short*)(ws + 32 * MB);   // 8 MB
  unsigned short* wob = (unsigned short*)(ws + 40 * MB);   // 8 MB
  unsigned short* Qb  = (unsigned short*)(ws + 48 * MB);   // 16 MB
  unsigned short* Kb  = (unsigned short*)(ws + 64 * MB);   // 16 MB
  unsigned short* Vtb = (unsigned short*)(ws + 80 * MB);   // 16 MB
  float* cosT = (float*)(ws + 96 * MB);                    // 0.5 MB
  float* sinT = (float*)(ws + 96 * MB + 524288);           // 0.5 MB
  unsigned short* ctxb = xb;  // x_bf16 dead after QKV GEMMs

  const int M = B_ * S_;  // 4096

  conv_kernel<<<8192, 256, 0, stream>>>(x, xb, (B_ * S_ * D_) / 4);
  conv_kernel<<<4096, 256, 0, stream>>>(wq, wqb, (D_ * D_) / 4);
  conv_kernel<<<4096, 256, 0, stream>>>(wk, wkb, (D_ * D_) / 4);
  conv_kernel<<<4096, 256, 0, stream>>>(wv, wvb, (D_ * D_) / 4);
  conv_kernel<<<4096, 256, 0, stream>>>(wo, wob, (D_ * D_) / 4);
  rope_table_kernel<<<512, 256, 0, stream>>>(cosT, sinT);

  dim3 ggrid(M / 128, D_ / 128);
  gemm_bt<0><<<ggrid, 256, 0, stream>>>(xb, wqb, Qb, nullptr, nullptr, nullptr, M, D_, D_);
  gemm_bt<2><<<ggrid, 256, 0, stream>>>(xb, wkb, Kb, nullptr, cosT, sinT, M, D_, D_);
  gemm_bt<3><<<ggrid, 256, 0, stream>>>(xb, wvb, Vtb, nullptr, nullptr, nullptr, M, D_, D_);

  attn_kernel<<<dim3(S_ / 64, B_ * H_), 256, 0, stream>>>(Qb, Kb, Vtb, ctxb, cosT, sinT);

  gemm_bt<1><<<ggrid, 256, 0, stream>>>(ctxb, wob, nullptr, out, nullptr, nullptr, M, D_, D_);
}

// Round 4
// 330.157 us; speedup vs baseline: 1.8671x; 1.0988x over previous
//
#include <hip/hip_runtime.h>
#include <hip/hip_bf16.h>
#include <stdint.h>

// RoPE attention, B=2 S=2048 D=2048 H=16 hd=128.
// conv(all f32->bf16, one kernel) -> Q GEMM | K GEMM(+rope) | V GEMM(->Vt)
//   -> flash attention (QBLK=32/wave, shared K/V fragments, XCD swizzle,
//      swapped-QK^T in-register softmax, defer-max, global_load_lds staging)
//   -> output GEMM (f32).

typedef __attribute__((ext_vector_type(4))) float f32x4;
typedef __attribute__((ext_vector_type(8))) short bf16x8;

typedef __attribute__((address_space(3))) unsigned int lds_u32;
typedef __attribute__((address_space(1))) const unsigned int gbl_u32;

__device__ __forceinline__ void async16(const void* g, void* l) {
  __builtin_amdgcn_global_load_lds((gbl_u32*)g, (lds_u32*)l, 16, 0, 0);
}

__device__ __forceinline__ float bf_to_f(unsigned short u) {
  union { unsigned int i; float f; } v; v.i = ((unsigned int)u) << 16; return v.f;
}
__device__ __forceinline__ unsigned short f_to_bf(float f) {
  union { float f; unsigned int i; } v; v.f = f;
  unsigned int r = v.i + 0x7FFFu + ((v.i >> 16) & 1u);  // RNE
  return (unsigned short)(r >> 16);
}

#define B_ 2
#define S_ 2048
#define D_ 2048
#define H_ 16
#define HD_ 128

// ---------------- fused f32 -> bf16 convert for x + 4 weights ----------------
// chunks of 4 floats: x = 2097152 chunks, each weight = 1048576 chunks.
__global__ __launch_bounds__(256) void conv_all(const float* __restrict__ x,
                                                const float* __restrict__ wq,
                                                const float* __restrict__ wk,
                                                const float* __restrict__ wv,
                                                const float* __restrict__ wo,
                                                unsigned short* __restrict__ xb,
                                                unsigned short* __restrict__ wb) {
  int i = blockIdx.x * 256 + threadIdx.x;  // [0, 6291456)
  const float* s;
  unsigned short* d;
  int off;
  if (i < 2097152) {
    s = x; d = xb; off = i;
  } else {
    int j = i - 2097152;
    int t = j >> 20;
    off = j & 1048575;
    s = (t == 0) ? wq : (t == 1) ? wk : (t == 2) ? wv : wo;
    d = wb + (size_t)t * 4194304;
  }
  float4 v = ((const float4*)s)[off];
  uint2 o;
  o.x = (unsigned int)f_to_bf(v.x) | ((unsigned int)f_to_bf(v.y) << 16);
  o.y = (unsigned int)f_to_bf(v.z) | ((unsigned int)f_to_bf(v.w) << 16);
  ((uint2*)d)[off] = o;
}

// ---------------- rope cos/sin table: [S][64] ----------------
__global__ __launch_bounds__(256) void rope_table_kernel(float* __restrict__ cosT,
                                                         float* __restrict__ sinT) {
  int i = blockIdx.x * 256 + threadIdx.x;  // S*64 entries
  int s = i >> 6, j = i & 63;
  float inv = powf(10000.0f, -(float)(2 * j) * (1.0f / 128.0f));
  float ang = (float)s * inv;
  float sv, cv;
  sincosf(ang, &sv, &cv);
  cosT[i] = cv;
  sinT[i] = sv;
}

// ---------------- GEMM: C[M,N] = A[M,K] * Bmat[N,K]^T -----------------------
// MODE 0: bf16 out. MODE 1: f32 out. MODE 2: bf16 out + RoPE (K projection).
// MODE 3: bf16 out written transposed into Vt[b*2048 + n][s] (V projection).
template <int MODE>
__global__ __launch_bounds__(256, 2) void gemm_bt(const unsigned short* __restrict__ A,
                                                  const unsigned short* __restrict__ Bm,
                                                  unsigned short* __restrict__ Cb,
                                                  float* __restrict__ Cf,
                                                  const float* __restrict__ cosT,
                                                  const float* __restrict__ sinT,
                                                  int M, int N, int K) {
  __shared__ unsigned short sA[128 * 32];
  __shared__ unsigned short sB[128 * 32];
  const int tid = threadIdx.x;
  const int l = tid & 63, wv = tid >> 6;
  const int lane15 = l & 15, lhi = l >> 4;
  const int wm = wv >> 1, wn = wv & 1;
  const int bm = blockIdx.x, bn = blockIdx.y;
  const unsigned short* Ag = A + (size_t)bm * 128 * K;
  const unsigned short* Bg = Bm + (size_t)bn * 128 * K;

  f32x4 acc[4][4];
  const f32x4 zero = {0.f, 0.f, 0.f, 0.f};
#pragma unroll
  for (int i = 0; i < 4; i++)
#pragma unroll
    for (int j = 0; j < 4; j++) acc[i][j] = zero;

  for (int k0 = 0; k0 < K; k0 += 32) {
    __syncthreads();
#pragma unroll
    for (int i = 0; i < 2; i++) {
      int c = i * 256 + tid;
      int row = c >> 2, col = (c & 3) << 3;
      async16(Ag + (size_t)row * K + k0 + col, &sA[c * 8]);
      async16(Bg + (size_t)row * K + k0 + col, &sB[c * 8]);
    }
    __syncthreads();

    bf16x8 af[4], bfr[4];
#pragma unroll
    for (int i = 0; i < 4; i++)
      af[i] = *(const bf16x8*)&sA[(wm * 64 + i * 16 + lane15) * 32 + lhi * 8];
#pragma unroll
    for (int j = 0; j < 4; j++)
      bfr[j] = *(const bf16x8*)&sB[(wn * 64 + j * 16 + lane15) * 32 + lhi * 8];
#pragma unroll
    for (int i = 0; i < 4; i++)
#pragma unroll
      for (int j = 0; j < 4; j++)
        acc[i][j] = __builtin_amdgcn_mfma_f32_16x16x32_bf16(af[i], bfr[j], acc[i][j], 0, 0, 0);
  }

  // epilogue: C/D layout col=lane&15, row=(lane>>4)*4+r
#pragma unroll
  for (int i = 0; i < 4; i++) {
    int m0 = bm * 128 + wm * 64 + i * 16 + lhi * 4;
#pragma unroll
    for (int j = 0; j < 4; j++) {
      int n = bn * 128 + wn * 64 + j * 16 + lane15;
      if constexpr (MODE == 0) {
#pragma unroll
        for (int r = 0; r < 4; r++) Cb[(size_t)(m0 + r) * N + n] = f_to_bf(acc[i][j][r]);
      } else if constexpr (MODE == 1) {
#pragma unroll
        for (int r = 0; r < 4; r++) Cf[(size_t)(m0 + r) * N + n] = acc[i][j][r];
      } else if constexpr (MODE == 2) {
        int s0 = m0 & (S_ - 1);
        int jp = (n & (HD_ - 1)) >> 1;
        int odd = n & 1;
#pragma unroll
        for (int r = 0; r < 4; r++) {
          float own = acc[i][j][r];
          float prt = __shfl_xor(own, 1);
          float c = cosT[(s0 + r) * 64 + jp];
          float sn = sinT[(s0 + r) * 64 + jp];
          float outv = odd ? fmaf(prt, sn, own * c) : own * c - prt * sn;
          Cb[(size_t)(m0 + r) * N + n] = f_to_bf(outv);
        }
      } else {  // MODE 3: Vt[b*2048 + n][s], 4 consecutive s packed
        int s0 = m0 & (S_ - 1);
        size_t row = (size_t)((m0 >> 11) * D_ + n);
        uint2 st;
        st.x = (unsigned int)f_to_bf(acc[i][j][0]) | ((unsigned int)f_to_bf(acc[i][j][1]) << 16);
        st.y = (unsigned int)f_to_bf(acc[i][j][2]) | ((unsigned int)f_to_bf(acc[i][j][3]) << 16);
        *(uint2*)(Cb + row * S_ + s0) = st;
      }
    }
  }
}

// ---------------- flash attention ----------------
// grid (16, 32): 512 blocks, 2/CU, all resident. XCD-swizzled work assignment:
// each XCD owns 4 heads (4 MB KV = its L2). 4 waves x QBLK=32 (2 stripes of 16);
// K/V LDS fragments shared across the 2 stripes (halves LDS read per FLOP).
__global__ __launch_bounds__(256, 2) void attn_kernel(const unsigned short* __restrict__ Q,
                                                      const unsigned short* __restrict__ K,
                                                      const unsigned short* __restrict__ Vt,
                                                      unsigned short* __restrict__ ctx,
                                                      const float* __restrict__ cosT,
                                                      const float* __restrict__ sinT) {
  __shared__ unsigned short sK[64 * 128];
  __shared__ unsigned short sV[128 * 64];
  __shared__ unsigned short sP[4][32 * 72];
  const int tid = threadIdx.x, l = tid & 63, w = tid >> 6;
  const int lane15 = l & 15, lhi = l >> 4;
  // XCD swizzle: wg -> (bh, qt). xcd = wg&7 owns bh in [xcd*4, xcd*4+4).
  const int wg = blockIdx.y * 16 + blockIdx.x;
  const int xcd = wg & 7, slot = wg >> 3;
  const int bh = xcd * 4 + (slot >> 4);
  const int qt = slot & 15;
  const int b = bh >> 4, h = bh & 15;
  const int q0 = qt * 128;
  const unsigned short* Kg = K + ((size_t)(b * S_)) * D_ + h * HD_;
  const unsigned short* Vg = Vt + ((size_t)bh * HD_) * S_;
  const float scale = 0.08838834764831845f;  // 1/sqrt(128)

  // Q load + RoPE + scale for both stripes (once per block; pairs in-lane)
  bf16x8 qf[2][4];
#pragma unroll
  for (int s = 0; s < 2; s++) {
    int s_q = q0 + w * 32 + s * 16 + lane15;
    const unsigned short* Qrow = Q + ((size_t)(b * S_ + s_q)) * D_ + h * HD_;
#pragma unroll
    for (int kc = 0; kc < 4; kc++) {
      int d0 = kc * 32 + lhi * 8;
      uint4 raw = *(const uint4*)(Qrow + d0);
      float4 cv = *(const float4*)(cosT + (size_t)s_q * 64 + (d0 >> 1));
      float4 sv = *(const float4*)(sinT + (size_t)s_q * 64 + (d0 >> 1));
      unsigned int u[4] = {raw.x, raw.y, raw.z, raw.w};
      float cc[4] = {cv.x, cv.y, cv.z, cv.w};
      float ss[4] = {sv.x, sv.y, sv.z, sv.w};
      unsigned int o[4];
#pragma unroll
      for (int p = 0; p < 4; p++) {
        float re = bf_to_f((unsigned short)(u[p] & 0xffffu));
        float im = bf_to_f((unsigned short)(u[p] >> 16));
        float orr = (re * cc[p] - im * ss[p]) * scale;
        float oi = (re * ss[p] + im * cc[p]) * scale;
        o[p] = (unsigned int)f_to_bf(orr) | ((unsigned int)f_to_bf(oi) << 16);
      }
      union { uint4 u4; bf16x8 v; } cvt;
      cvt.u4.x = o[0]; cvt.u4.y = o[1]; cvt.u4.z = o[2]; cvt.u4.w = o[3];
      qf[s][kc] = cvt.v;
    }
  }

  float mrun[2] = {-1e30f, -1e30f}, lrun[2] = {0.f, 0.f};
  const f32x4 zero = {0.f, 0.f, 0.f, 0.f};
  f32x4 oacc[2][8];
#pragma unroll
  for (int s = 0; s < 2; s++)
#pragma unroll
    for (int nf = 0; nf < 8; nf++) oacc[s][nf] = zero;

  for (int t = 0; t < 32; ++t) {
    __syncthreads();  // previous tile fully consumed
    // stage K tile (64x128): wave w rows [w*16, w*16+16); linear LDS dest,
    // pre-swizzled global source column (same XOR as the read side)
#pragma unroll
    for (int i = 0; i < 4; i++) {
      int row = w * 16 + i * 4 + (l >> 4);
      int colD = (l & 15) << 4;
      int colS = colD ^ ((row & 7) << 4);
      async16(Kg + (size_t)(t * 64 + row) * D_ + (colS >> 1),
              (char*)sK + row * 256 + colD);
    }
    // stage Vt tile (128x64): wave w rows [w*32, w*32+32)
#pragma unroll
    for (int i = 0; i < 4; i++) {
      int row = w * 32 + i * 8 + (l >> 3);
      int colD = (l & 7) << 4;
      int colS = colD ^ ((row & 7) << 4);
      async16(Vg + (size_t)row * S_ + t * 64 + (colS >> 1),
              (char*)sV + row * 128 + colD);
    }
    __syncthreads();  // staging complete

    // S^T = K Q^T for both stripes, kf shared: lane owns q=lane15, k=n*16+lhi*4+r
    f32x4 sacc[2][4];
#pragma unroll
    for (int s = 0; s < 2; s++)
#pragma unroll
      for (int n = 0; n < 4; n++) sacc[s][n] = zero;
#pragma unroll
    for (int n = 0; n < 4; n++) {
      int row = n * 16 + lane15;
#pragma unroll
      for (int kc = 0; kc < 4; kc++) {
        bf16x8 kf = *(const bf16x8*)((char*)sK + row * 256 +
                                     ((kc * 64 + lhi * 16) ^ ((row & 7) << 4)));
        sacc[0][n] = __builtin_amdgcn_mfma_f32_16x16x32_bf16(kf, qf[0][kc], sacc[0][n], 0, 0, 0);
        sacc[1][n] = __builtin_amdgcn_mfma_f32_16x16x32_bf16(kf, qf[1][kc], sacc[1][n], 0, 0, 0);
      }
    }

    // in-register online softmax per stripe (defer-max, THR=8)
#pragma unroll
    for (int s = 0; s < 2; s++) {
      float pmax = sacc[s][0][0];
#pragma unroll
      for (int n = 0; n < 4; n++)
#pragma unroll
        for (int r = 0; r < 4; r++) pmax = fmaxf(pmax, sacc[s][n][r]);
      pmax = fmaxf(pmax, __shfl_xor(pmax, 16));
      pmax = fmaxf(pmax, __shfl_xor(pmax, 32));
      if (!__all(pmax - mrun[s] <= 8.0f)) {
        float mnew = fmaxf(mrun[s], pmax);
        float alpha = __expf(mrun[s] - mnew);
        lrun[s] *= alpha;
        float af[4];
#pragma unroll
        for (int r = 0; r < 4; r++) af[r] = __shfl(alpha, lhi * 4 + r);
#pragma unroll
        for (int nf = 0; nf < 8; nf++)
#pragma unroll
          for (int r = 0; r < 4; r++) oacc[s][nf][r] *= af[r];
        mrun[s] = mnew;
      }
      const float l2e = 1.44269504f;
      float mb = mrun[s] * l2e;
      float rs = 0.f;
      float p[4][4];
#pragma unroll
      for (int n = 0; n < 4; n++)
#pragma unroll
        for (int r = 0; r < 4; r++) {
          float pv = exp2f(sacc[s][n][r] * l2e - mb);
          p[n][r] = pv;
          rs += pv;
        }
      rs += __shfl_xor(rs, 16);
      rs += __shfl_xor(rs, 32);
      lrun[s] += rs;
      // P -> per-wave LDS (A-layout: row=q, k contiguous), stride 72
#pragma unroll
      for (int n = 0; n < 4; n++) {
        uint2 st;
        st.x = (unsigned int)f_to_bf(p[n][0]) | ((unsigned int)f_to_bf(p[n][1]) << 16);
        st.y = (unsigned int)f_to_bf(p[n][2]) | ((unsigned int)f_to_bf(p[n][3]) << 16);
        *(uint2*)&sP[w][(s * 16 + lane15) * 72 + n * 16 + lhi * 4] = st;
      }
    }
    asm volatile("s_waitcnt lgkmcnt(0)" ::: "memory");
    __builtin_amdgcn_sched_barrier(0);
    bf16x8 pf[2][2];
#pragma unroll
    for (int s = 0; s < 2; s++)
#pragma unroll
      for (int kc = 0; kc < 2; kc++)
        pf[s][kc] = *(const bf16x8*)&sP[w][(s * 16 + lane15) * 72 + kc * 32 + lhi * 8];

    // O += P * V, vf shared across stripes
#pragma unroll
    for (int nf = 0; nf < 8; nf++) {
      int row = nf * 16 + lane15;
#pragma unroll
      for (int kc = 0; kc < 2; kc++) {
        bf16x8 vf = *(const bf16x8*)((char*)sV + row * 128 +
                                     ((kc * 64 + lhi * 16) ^ ((row & 7) << 4)));
        oacc[0][nf] = __builtin_amdgcn_mfma_f32_16x16x32_bf16(pf[0][kc], vf, oacc[0][nf], 0, 0, 0);
        oacc[1][nf] = __builtin_amdgcn_mfma_f32_16x16x32_bf16(pf[1][kc], vf, oacc[1][nf], 0, 0, 0);
      }
    }
  }

  // epilogue: oacc[s] rows q=lhi*4+r, cols d=nf*16+lane15
#pragma unroll
  for (int s = 0; s < 2; s++) {
    float inv = 1.0f / lrun[s];
    float invr[4];
#pragma unroll
    for (int r = 0; r < 4; r++) invr[r] = __shfl(inv, lhi * 4 + r);
    unsigned short* Og = ctx + ((size_t)(b * S_ + q0 + w * 32 + s * 16)) * D_ + h * HD_;
#pragma unroll
    for (int r = 0; r < 4; r++) {
      int qrow = lhi * 4 + r;
#pragma unroll
      for (int nf = 0; nf < 8; nf++)
        Og[(size_t)qrow * D_ + nf * 16 + lane15] = f_to_bf(oacc[s][nf][r] * invr[r]);
    }
  }
}

// ---------------- launcher ----------------
extern "C" void kernel_launch(void* const* d_in, const int* in_sizes, int n_in,
                              void* d_out, int out_size, void* d_ws, size_t ws_size,
                              hipStream_t stream) {
  (void)in_sizes; (void)n_in; (void)out_size; (void)ws_size;
  const float* x = (const float*)d_in[0];
  const float* wq = (const float*)d_in[1];
  const float* wk = (const float*)d_in[2];
  const float* wv = (const float*)d_in[3];
  const float* wo = (const float*)d_in[4];
  float* out = (float*)d_out;

  char* ws = (char*)d_ws;
  const size_t MB = 1024 * 1024;
  unsigned short* xb  = (unsigned short*)(ws + 0 * MB);    // 16 MB; later aliased as ctx
  unsigned short* wqb = (unsigned short*)(ws + 16 * MB);   // 8 MB (wq..wo contiguous)
  unsigned short* wkb = (unsigned short*)(ws + 24 * MB);
  unsigned short* wvb = (unsigned short*)(ws + 32 * MB);
  unsigned short* wob = (unsigned short*)(ws + 40 * MB);
  unsigned short* Qb  = (unsigned short*)(ws + 48 * MB);   // 16 MB
  unsigned short* Kb  = (unsigned short*)(ws + 64 * MB);   // 16 MB
  unsigned short* Vtb = (unsigned short*)(ws + 80 * MB);   // 16 MB
  float* cosT = (float*)(ws + 96 * MB);                    // 0.5 MB
  float* sinT = (float*)(ws + 96 * MB + 524288);           // 0.5 MB
  unsigned short* ctxb = xb;  // x_bf16 dead after QKV GEMMs

  const int M = B_ * S_;  // 4096

  conv_all<<<24576, 256, 0, stream>>>(x, wq, wk, wv, wo, xb, wqb);
  rope_table_kernel<<<512, 256, 0, stream>>>(cosT, sinT);

  dim3 ggrid(M / 128, D_ / 128);
  gemm_bt<0><<<ggrid, 256, 0, stream>>>(xb, wqb, Qb, nullptr, nullptr, nullptr, M, D_, D_);
  gemm_bt<2><<<ggrid, 256, 0, stream>>>(xb, wkb, Kb, nullptr, cosT, sinT, M, D_, D_);
  gemm_bt<3><<<ggrid, 256, 0, stream>>>(xb, wvb, Vtb, nullptr, nullptr, nullptr, M, D_, D_);

  attn_kernel<<<dim3(16, 32), 256, 0, stream>>>(Qb, Kb, Vtb, ctxb, cosT, sinT);

  gemm_bt<1><<<ggrid, 256, 0, stream>>>(ctxb, wob, nullptr, out, nullptr, nullptr, M, D_, D_);
}

// Round 5
// 318.936 us; speedup vs baseline: 1.9328x; 1.0352x over previous
//
#include <hip/hip_runtime.h>
#include <hip/hip_bf16.h>
#include <stdint.h>

// RoPE attention, B=2 S=2048 D=2048 H=16 hd=128.
// conv(all f32->bf16, one kernel) -> Q GEMM | K GEMM(+rope) | V GEMM(->Vt)
//   -> flash attention (8-wave block, double-buffered async staging,
//      QBLK=32/wave shared fragments, XCD swizzle, swapped-QK^T in-register
//      softmax, defer-max, cvt_pk bf16 pack, setprio) -> output GEMM (f32).

typedef __attribute__((ext_vector_type(4))) float f32x4;
typedef __attribute__((ext_vector_type(8))) short bf16x8;

typedef __attribute__((address_space(3))) unsigned int lds_u32;
typedef __attribute__((address_space(1))) const unsigned int gbl_u32;

__device__ __forceinline__ void async16(const void* g, void* l) {
  __builtin_amdgcn_global_load_lds((gbl_u32*)g, (lds_u32*)l, 16, 0, 0);
}

__device__ __forceinline__ float bf_to_f(unsigned short u) {
  union { unsigned int i; float f; } v; v.i = ((unsigned int)u) << 16; return v.f;
}
__device__ __forceinline__ unsigned short f_to_bf(float f) {
  union { float f; unsigned int i; } v; v.f = f;
  unsigned int r = v.i + 0x7FFFu + ((v.i >> 16) & 1u);  // RNE
  return (unsigned short)(r >> 16);
}
__device__ __forceinline__ unsigned int cvt_pk_bf16(float lo, float hi) {
  unsigned int r;
  asm("v_cvt_pk_bf16_f32 %0, %1, %2" : "=v"(r) : "v"(lo), "v"(hi));
  return r;
}

#define B_ 2
#define S_ 2048
#define D_ 2048
#define H_ 16
#define HD_ 128

// ---------------- fused f32 -> bf16 convert for x + 4 weights ----------------
__global__ __launch_bounds__(256) void conv_all(const float* __restrict__ x,
                                                const float* __restrict__ wq,
                                                const float* __restrict__ wk,
                                                const float* __restrict__ wv,
                                                const float* __restrict__ wo,
                                                unsigned short* __restrict__ xb,
                                                unsigned short* __restrict__ wb) {
  int i = blockIdx.x * 256 + threadIdx.x;  // [0, 6291456)
  const float* s;
  unsigned short* d;
  int off;
  if (i < 2097152) {
    s = x; d = xb; off = i;
  } else {
    int j = i - 2097152;
    int t = j >> 20;
    off = j & 1048575;
    s = (t == 0) ? wq : (t == 1) ? wk : (t == 2) ? wv : wo;
    d = wb + (size_t)t * 4194304;
  }
  float4 v = ((const float4*)s)[off];
  uint2 o;
  o.x = (unsigned int)f_to_bf(v.x) | ((unsigned int)f_to_bf(v.y) << 16);
  o.y = (unsigned int)f_to_bf(v.z) | ((unsigned int)f_to_bf(v.w) << 16);
  ((uint2*)d)[off] = o;
}

// ---------------- rope cos/sin table: [S][64] ----------------
__global__ __launch_bounds__(256) void rope_table_kernel(float* __restrict__ cosT,
                                                         float* __restrict__ sinT) {
  int i = blockIdx.x * 256 + threadIdx.x;  // S*64 entries
  int s = i >> 6, j = i & 63;
  float inv = powf(10000.0f, -(float)(2 * j) * (1.0f / 128.0f));
  float ang = (float)s * inv;
  float sv, cv;
  sincosf(ang, &sv, &cv);
  cosT[i] = cv;
  sinT[i] = sv;
}

// ---------------- GEMM: C[M,N] = A[M,K] * Bmat[N,K]^T -----------------------
// MODE 0: bf16 out. MODE 1: f32 out. MODE 2: bf16 out + RoPE (K projection).
// MODE 3: bf16 out written transposed into Vt[b*2048 + n][s] (V projection).
template <int MODE>
__global__ __launch_bounds__(256, 2) void gemm_bt(const unsigned short* __restrict__ A,
                                                  const unsigned short* __restrict__ Bm,
                                                  unsigned short* __restrict__ Cb,
                                                  float* __restrict__ Cf,
                                                  const float* __restrict__ cosT,
                                                  const float* __restrict__ sinT,
                                                  int M, int N, int K) {
  __shared__ unsigned short sA[128 * 32];
  __shared__ unsigned short sB[128 * 32];
  const int tid = threadIdx.x;
  const int l = tid & 63, wv = tid >> 6;
  const int lane15 = l & 15, lhi = l >> 4;
  const int wm = wv >> 1, wn = wv & 1;
  const int bm = blockIdx.x, bn = blockIdx.y;
  const unsigned short* Ag = A + (size_t)bm * 128 * K;
  const unsigned short* Bg = Bm + (size_t)bn * 128 * K;

  f32x4 acc[4][4];
  const f32x4 zero = {0.f, 0.f, 0.f, 0.f};
#pragma unroll
  for (int i = 0; i < 4; i++)
#pragma unroll
    for (int j = 0; j < 4; j++) acc[i][j] = zero;

  for (int k0 = 0; k0 < K; k0 += 32) {
    __syncthreads();
#pragma unroll
    for (int i = 0; i < 2; i++) {
      int c = i * 256 + tid;
      int row = c >> 2, col = (c & 3) << 3;
      async16(Ag + (size_t)row * K + k0 + col, &sA[c * 8]);
      async16(Bg + (size_t)row * K + k0 + col, &sB[c * 8]);
    }
    __syncthreads();

    bf16x8 af[4], bfr[4];
#pragma unroll
    for (int i = 0; i < 4; i++)
      af[i] = *(const bf16x8*)&sA[(wm * 64 + i * 16 + lane15) * 32 + lhi * 8];
#pragma unroll
    for (int j = 0; j < 4; j++)
      bfr[j] = *(const bf16x8*)&sB[(wn * 64 + j * 16 + lane15) * 32 + lhi * 8];
#pragma unroll
    for (int i = 0; i < 4; i++)
#pragma unroll
      for (int j = 0; j < 4; j++)
        acc[i][j] = __builtin_amdgcn_mfma_f32_16x16x32_bf16(af[i], bfr[j], acc[i][j], 0, 0, 0);
  }

  // epilogue: C/D layout col=lane&15, row=(lane>>4)*4+r
#pragma unroll
  for (int i = 0; i < 4; i++) {
    int m0 = bm * 128 + wm * 64 + i * 16 + lhi * 4;
#pragma unroll
    for (int j = 0; j < 4; j++) {
      int n = bn * 128 + wn * 64 + j * 16 + lane15;
      if constexpr (MODE == 0) {
#pragma unroll
        for (int r = 0; r < 4; r++) Cb[(size_t)(m0 + r) * N + n] = f_to_bf(acc[i][j][r]);
      } else if constexpr (MODE == 1) {
#pragma unroll
        for (int r = 0; r < 4; r++) Cf[(size_t)(m0 + r) * N + n] = acc[i][j][r];
      } else if constexpr (MODE == 2) {
        int s0 = m0 & (S_ - 1);
        int jp = (n & (HD_ - 1)) >> 1;
        int odd = n & 1;
#pragma unroll
        for (int r = 0; r < 4; r++) {
          float own = acc[i][j][r];
          float prt = __shfl_xor(own, 1);
          float c = cosT[(s0 + r) * 64 + jp];
          float sn = sinT[(s0 + r) * 64 + jp];
          float outv = odd ? fmaf(prt, sn, own * c) : own * c - prt * sn;
          Cb[(size_t)(m0 + r) * N + n] = f_to_bf(outv);
        }
      } else {  // MODE 3: Vt[b*2048 + n][s], 4 consecutive s packed
        int s0 = m0 & (S_ - 1);
        size_t row = (size_t)((m0 >> 11) * D_ + n);
        uint2 st;
        st.x = (unsigned int)f_to_bf(acc[i][j][0]) | ((unsigned int)f_to_bf(acc[i][j][1]) << 16);
        st.y = (unsigned int)f_to_bf(acc[i][j][2]) | ((unsigned int)f_to_bf(acc[i][j][3]) << 16);
        *(uint2*)(Cb + row * S_ + s0) = st;
      }
    }
  }
}

// ---------------- flash attention ----------------
// grid (8, 32): 256 blocks of 512 threads = 1 block/CU.
// XCD swizzle: xcd = wg&7 = blockIdx.x owns bh in [bx*4, bx*4+4) (4 MB KV = L2).
// 8 waves x QBLK=32 (2 stripes of 16); waves 0-3 stage K, 4-7 stage V.
// Double-buffered LDS; one __syncthreads per tile (drains prev loads, ~free).
__global__ __launch_bounds__(512, 2) void attn_kernel(const unsigned short* __restrict__ Q,
                                                      const unsigned short* __restrict__ K,
                                                      const unsigned short* __restrict__ Vt,
                                                      unsigned short* __restrict__ ctx,
                                                      const float* __restrict__ cosT,
                                                      const float* __restrict__ sinT) {
  __shared__ unsigned short sK[2][64 * 128];
  __shared__ unsigned short sV[2][128 * 64];
  __shared__ unsigned short sP[8][32 * 72];
  const int tid = threadIdx.x, l = tid & 63, w = tid >> 6;
  const int lane15 = l & 15, lhi = l >> 4;
  const int bh = blockIdx.x * 4 + (blockIdx.y >> 3);
  const int qt = blockIdx.y & 7;
  const int b = bh >> 4, h = bh & 15;
  const int q0 = qt * 256;
  const unsigned short* Kg = K + ((size_t)(b * S_)) * D_ + h * HD_;
  const unsigned short* Vg = Vt + ((size_t)bh * HD_) * S_;
  const float scale = 0.08838834764831845f;  // 1/sqrt(128)

  // staging role: waves 0-3 -> K tile (64x128), waves 4-7 -> V tile (128x64).
  // Per-thread 4 global pointers (pre-swizzled source col), advanced per tile.
  const unsigned short* gp0;
  const unsigned short* gp1;
  const unsigned short* gp2;
  const unsigned short* gp3;
  unsigned int ldsOff[4];
  int gstride;
  if (w < 4) {
    const unsigned short* t0;
#pragma unroll
    for (int i = 0; i < 4; i++) {
      int row = w * 16 + i * 4 + (l >> 4);
      int colD = (l & 15) << 4;
      int colS = colD ^ ((row & 7) << 4);
      t0 = Kg + (size_t)row * D_ + (colS >> 1);
      if (i == 0) gp0 = t0; else if (i == 1) gp1 = t0; else if (i == 2) gp2 = t0; else gp3 = t0;
      ldsOff[i] = row * 256 + colD;
    }
    gstride = 64 * D_;
  } else {
    const unsigned short* t0;
#pragma unroll
    for (int i = 0; i < 4; i++) {
      int row = (w - 4) * 32 + i * 8 + (l >> 3);
      int colD = (l & 7) << 4;
      int colS = colD ^ ((row & 7) << 4);
      t0 = Vg + (size_t)row * S_ + (colS >> 1);
      if (i == 0) gp0 = t0; else if (i == 1) gp1 = t0; else if (i == 2) gp2 = t0; else gp3 = t0;
      ldsOff[i] = row * 128 + colD;
    }
    gstride = 64;
  }

  // Q load + RoPE + scale for both stripes (once per block; pairs in-lane)
  bf16x8 qf[2][4];
#pragma unroll
  for (int s = 0; s < 2; s++) {
    int s_q = q0 + w * 32 + s * 16 + lane15;
    const unsigned short* Qrow = Q + ((size_t)(b * S_ + s_q)) * D_ + h * HD_;
#pragma unroll
    for (int kc = 0; kc < 4; kc++) {
      int d0 = kc * 32 + lhi * 8;
      uint4 raw = *(const uint4*)(Qrow + d0);
      float4 cv = *(const float4*)(cosT + (size_t)s_q * 64 + (d0 >> 1));
      float4 sv = *(const float4*)(sinT + (size_t)s_q * 64 + (d0 >> 1));
      unsigned int u[4] = {raw.x, raw.y, raw.z, raw.w};
      float cc[4] = {cv.x, cv.y, cv.z, cv.w};
      float ss[4] = {sv.x, sv.y, sv.z, sv.w};
      unsigned int o[4];
#pragma unroll
      for (int p = 0; p < 4; p++) {
        float re = bf_to_f((unsigned short)(u[p] & 0xffffu));
        float im = bf_to_f((unsigned short)(u[p] >> 16));
        float orr = (re * cc[p] - im * ss[p]) * scale;
        float oi = (re * ss[p] + im * cc[p]) * scale;
        o[p] = (unsigned int)f_to_bf(orr) | ((unsigned int)f_to_bf(oi) << 16);
      }
      union { uint4 u4; bf16x8 v; } cvt;
      cvt.u4.x = o[0]; cvt.u4.y = o[1]; cvt.u4.z = o[2]; cvt.u4.w = o[3];
      qf[s][kc] = cvt.v;
    }
  }

  float mrun[2] = {-1e30f, -1e30f}, lrun[2] = {0.f, 0.f};
  const f32x4 zero = {0.f, 0.f, 0.f, 0.f};
  f32x4 oacc[2][8];
#pragma unroll
  for (int s = 0; s < 2; s++)
#pragma unroll
    for (int nf = 0; nf < 8; nf++) oacc[s][nf] = zero;

  // prologue: stage tile 0 into buffer 0
  {
    char* base = (w < 4) ? (char*)&sK[0][0] : (char*)&sV[0][0];
    async16(gp0, base + ldsOff[0]);
    async16(gp1, base + ldsOff[1]);
    async16(gp2, base + ldsOff[2]);
    async16(gp3, base + ldsOff[3]);
    gp0 += gstride; gp1 += gstride; gp2 += gstride; gp3 += gstride;
  }

  for (int t = 0; t < 32; ++t) {
    const int cur = t & 1;
    // Drains prev-iteration loads (they had a full compute phase to land)
    // and gates buffer reuse. Single barrier per tile.
    __syncthreads();
    if (t < 31) {  // issue next tile's loads into the other buffer
      char* base = (w < 4) ? (char*)&sK[cur ^ 1][0] : (char*)&sV[cur ^ 1][0];
      async16(gp0, base + ldsOff[0]);
      async16(gp1, base + ldsOff[1]);
      async16(gp2, base + ldsOff[2]);
      async16(gp3, base + ldsOff[3]);
      gp0 += gstride; gp1 += gstride; gp2 += gstride; gp3 += gstride;
    }
    const unsigned short* sKc = sK[cur];
    const unsigned short* sVc = sV[cur];

    // S^T = K Q^T for both stripes, kf shared: lane owns q=lane15, k=n*16+lhi*4+r
    f32x4 sacc[2][4];
#pragma unroll
    for (int s = 0; s < 2; s++)
#pragma unroll
      for (int n = 0; n < 4; n++) sacc[s][n] = zero;
    __builtin_amdgcn_s_setprio(1);
#pragma unroll
    for (int n = 0; n < 4; n++) {
      int row = n * 16 + lane15;
#pragma unroll
      for (int kc = 0; kc < 4; kc++) {
        bf16x8 kf = *(const bf16x8*)((const char*)sKc + row * 256 +
                                     ((kc * 64 + lhi * 16) ^ ((row & 7) << 4)));
        sacc[0][n] = __builtin_amdgcn_mfma_f32_16x16x32_bf16(kf, qf[0][kc], sacc[0][n], 0, 0, 0);
        sacc[1][n] = __builtin_amdgcn_mfma_f32_16x16x32_bf16(kf, qf[1][kc], sacc[1][n], 0, 0, 0);
      }
    }
    __builtin_amdgcn_s_setprio(0);

    // in-register online softmax per stripe (defer-max, THR=8)
#pragma unroll
    for (int s = 0; s < 2; s++) {
      float m0 = fmaxf(fmaxf(sacc[s][0][0], sacc[s][0][1]), fmaxf(sacc[s][0][2], sacc[s][0][3]));
      float m1 = fmaxf(fmaxf(sacc[s][1][0], sacc[s][1][1]), fmaxf(sacc[s][1][2], sacc[s][1][3]));
      float m2 = fmaxf(fmaxf(sacc[s][2][0], sacc[s][2][1]), fmaxf(sacc[s][2][2], sacc[s][2][3]));
      float m3 = fmaxf(fmaxf(sacc[s][3][0], sacc[s][3][1]), fmaxf(sacc[s][3][2], sacc[s][3][3]));
      float pmax = fmaxf(fmaxf(m0, m1), fmaxf(m2, m3));
      pmax = fmaxf(pmax, __shfl_xor(pmax, 16));
      pmax = fmaxf(pmax, __shfl_xor(pmax, 32));
      if (!__all(pmax - mrun[s] <= 8.0f)) {
        float mnew = fmaxf(mrun[s], pmax);
        float alpha = __expf(mrun[s] - mnew);
        lrun[s] *= alpha;
        float af[4];
#pragma unroll
        for (int r = 0; r < 4; r++) af[r] = __shfl(alpha, lhi * 4 + r);
#pragma unroll
        for (int nf = 0; nf < 8; nf++)
#pragma unroll
          for (int r = 0; r < 4; r++) oacc[s][nf][r] *= af[r];
        mrun[s] = mnew;
      }
      const float l2e = 1.44269504f;
      float mb = mrun[s] * l2e;
      float rs = 0.f;
      float p[4][4];
#pragma unroll
      for (int n = 0; n < 4; n++)
#pragma unroll
        for (int r = 0; r < 4; r++) {
          float pv = exp2f(sacc[s][n][r] * l2e - mb);
          p[n][r] = pv;
          rs += pv;
        }
      rs += __shfl_xor(rs, 16);
      rs += __shfl_xor(rs, 32);
      lrun[s] += rs;
      // P -> per-wave LDS (A-layout: row=q, k contiguous), stride 72
#pragma unroll
      for (int n = 0; n < 4; n++) {
        uint2 st;
        st.x = cvt_pk_bf16(p[n][0], p[n][1]);
        st.y = cvt_pk_bf16(p[n][2], p[n][3]);
        *(uint2*)&sP[w][(s * 16 + lane15) * 72 + n * 16 + lhi * 4] = st;
      }
    }
    // wave-local cross-lane write->read fence
    asm volatile("s_waitcnt lgkmcnt(0)" ::: "memory");
    __builtin_amdgcn_sched_barrier(0);
    bf16x8 pf[2][2];
#pragma unroll
    for (int s = 0; s < 2; s++)
#pragma unroll
      for (int kc = 0; kc < 2; kc++)
        pf[s][kc] = *(const bf16x8*)&sP[w][(s * 16 + lane15) * 72 + kc * 32 + lhi * 8];

    // O += P * V, vf shared across stripes
    __builtin_amdgcn_s_setprio(1);
#pragma unroll
    for (int nf = 0; nf < 8; nf++) {
      int row = nf * 16 + lane15;
#pragma unroll
      for (int kc = 0; kc < 2; kc++) {
        bf16x8 vf = *(const bf16x8*)((const char*)sVc + row * 128 +
                                     ((kc * 64 + lhi * 16) ^ ((row & 7) << 4)));
        oacc[0][nf] = __builtin_amdgcn_mfma_f32_16x16x32_bf16(pf[0][kc], vf, oacc[0][nf], 0, 0, 0);
        oacc[1][nf] = __builtin_amdgcn_mfma_f32_16x16x32_bf16(pf[1][kc], vf, oacc[1][nf], 0, 0, 0);
      }
    }
    __builtin_amdgcn_s_setprio(0);
  }

  // epilogue: oacc[s] rows q=lhi*4+r, cols d=nf*16+lane15
#pragma unroll
  for (int s = 0; s < 2; s++) {
    float inv = 1.0f / lrun[s];
    float invr[4];
#pragma unroll
    for (int r = 0; r < 4; r++) invr[r] = __shfl(inv, lhi * 4 + r);
    unsigned short* Og = ctx + ((size_t)(b * S_ + q0 + w * 32 + s * 16)) * D_ + h * HD_;
#pragma unroll
    for (int r = 0; r < 4; r++) {
      int qrow = lhi * 4 + r;
#pragma unroll
      for (int nf = 0; nf < 8; nf++)
        Og[(size_t)qrow * D_ + nf * 16 + lane15] = f_to_bf(oacc[s][nf][r] * invr[r]);
    }
  }
}

// ---------------- launcher ----------------
extern "C" void kernel_launch(void* const* d_in, const int* in_sizes, int n_in,
                              void* d_out, int out_size, void* d_ws, size_t ws_size,
                              hipStream_t stream) {
  (void)in_sizes; (void)n_in; (void)out_size; (void)ws_size;
  const float* x = (const float*)d_in[0];
  const float* wq = (const float*)d_in[1];
  const float* wk = (const float*)d_in[2];
  const float* wv = (const float*)d_in[3];
  const float* wo = (const float*)d_in[4];
  float* out = (float*)d_out;

  char* ws = (char*)d_ws;
  const size_t MB = 1024 * 1024;
  unsigned short* xb  = (unsigned short*)(ws + 0 * MB);    // 16 MB; later aliased as ctx
  unsigned short* wqb = (unsigned short*)(ws + 16 * MB);   // 8 MB (wq..wo contiguous)
  unsigned short* wkb = (unsigned short*)(ws + 24 * MB);
  unsigned short* wvb = (unsigned short*)(ws + 32 * MB);
  unsigned short* wob = (unsigned short*)(ws + 40 * MB);
  unsigned short* Qb  = (unsigned short*)(ws + 48 * MB);   // 16 MB
  unsigned short* Kb  = (unsigned short*)(ws + 64 * MB);   // 16 MB
  unsigned short* Vtb = (unsigned short*)(ws + 80 * MB);   // 16 MB
  float* cosT = (float*)(ws + 96 * MB);                    // 0.5 MB
  float* sinT = (float*)(ws + 96 * MB + 524288);           // 0.5 MB
  unsigned short* ctxb = xb;  // x_bf16 dead after QKV GEMMs

  const int M = B_ * S_;  // 4096

  conv_all<<<24576, 256, 0, stream>>>(x, wq, wk, wv, wo, xb, wqb);
  rope_table_kernel<<<512, 256, 0, stream>>>(cosT, sinT);

  dim3 ggrid(M / 128, D_ / 128);
  gemm_bt<0><<<ggrid, 256, 0, stream>>>(xb, wqb, Qb, nullptr, nullptr, nullptr, M, D_, D_);
  gemm_bt<2><<<ggrid, 256, 0, stream>>>(xb, wkb, Kb, nullptr, cosT, sinT, M, D_, D_);
  gemm_bt<3><<<ggrid, 256, 0, stream>>>(xb, wvb, Vtb, nullptr, nullptr, nullptr, M, D_, D_);

  attn_kernel<<<dim3(8, 32), 512, 0, stream>>>(Qb, Kb, Vtb, ctxb, cosT, sinT);

  gemm_bt<1><<<ggrid, 256, 0, stream>>>(ctxb, wob, nullptr, out, nullptr, nullptr, M, D_, D_);
}